// Round 11
// baseline (4360.580 us; speedup 1.0000x reference)
//
#include <hip/hip_runtime.h>

#define HID 768
#define WPB 16     // words per tile
#define ROWS 64    // subword rows per tile
#define BK 64      // K-chunk width
#define NCH 12     // 768 / 64 K-chunks
#define NSTRIP 4   // N split: 4 strips x 192 cols

typedef __attribute__((ext_vector_type(4))) float f32x4;
typedef __attribute__((ext_vector_type(8))) short s16x8;
typedef __attribute__((ext_vector_type(4))) short s16x4;

__device__ inline short f2bf(float f) {
  unsigned u = __builtin_bit_cast(unsigned, f);
  u = (u + 0x7fffu + ((u >> 16) & 1u)) >> 16;
  return (short)(unsigned short)u;
}
__device__ inline float fast_tanh(float v) {
  float e = exp2f(v * 2.885390081777927f);   // e^{2v}
  return 1.0f - 2.0f * __builtin_amdgcn_rcpf(e + 1.0f);
}
__device__ inline s16x8 pack8(f32x4 f0, f32x4 f1) {
  s16x8 p;
  p[0]=f2bf(f0[0]); p[1]=f2bf(f0[1]); p[2]=f2bf(f0[2]); p[3]=f2bf(f0[3]);
  p[4]=f2bf(f1[0]); p[5]=f2bf(f1[1]); p[6]=f2bf(f1[2]); p[7]=f2bf(f1[3]);
  return p;
}
__device__ inline s16x4 pack4(f32x4 f) {
  s16x4 p;
  p[0]=f2bf(f[0]); p[1]=f2bf(f[1]); p[2]=f2bf(f[2]); p[3]=f2bf(f[3]);
  return p;
}

// ---- pre-pass: W fp32 -> bf16 in MFMA FRAGMENT ORDER (verified r7-r10) ----
__global__ void wconv_kernel(const float* __restrict__ W, short* __restrict__ Wb, int n64) {
  int gid = blockIdx.x * blockDim.x + threadIdx.x;
  if (gid >= n64) return;                  // n64 = 24*48*64 = 73728
  int lane = gid & 63;
  int frag = gid >> 6;
  int kc = frag / 48;                      // 0..23
  int t  = frag - kc * 48;                 // 0..47
  int col = t * 16 + (lane & 15);
  int k0  = kc * 32 + (lane >> 4) * 8;
  const float* src = W + (size_t)col * HID + k0;
  f32x4 f0 = *(const f32x4*)src;
  f32x4 f1 = *(const f32x4*)(src + 4);
  *(s16x8*)(Wb + (size_t)gid * 8) = pack8(f0, f1);
}

// ==== main path: 4-wave blocks, N split across NSTRIP blocks/tile ====
// Each block: 64 rows x 192 cols scorer-GEMM; per-row partial tanh-dot ->
// device atomicAdd into s_glob. Last strip-block of a tile (counter
// handshake) performs the pooling epilogue with x still L2/L3-warm.
__global__ __launch_bounds__(256, 3) void gemm_split(
    const float* __restrict__ x, const short* __restrict__ Wb,
    const float* __restrict__ bias, const float* __restrict__ scw,
    const int* __restrict__ mapping, float* __restrict__ out,
    int num_words, float* __restrict__ s_glob, int* __restrict__ cnt)
{
  __shared__ short Abuf[2 * ROWS * BK];   // 16 KB, XOR-swizzled, double-buffered
  __shared__ float s_lds[ROWS];
  __shared__ int lastflag;

  const int tid = threadIdx.x;
  const int bid = blockIdx.x;
  const int tile = bid >> 2;
  const int strip = bid & 3;
  const int w0 = tile * WPB;
  const int wlast = min(w0 + WPB - 1, num_words - 1);
  const int r0 = mapping[2 * w0];
  const int r1 = mapping[2 * wlast + 1];
  const int nrows = min(r1 - r0, ROWS);

  // --- staging: 256 thr, each 4 consecutive f32x4 slots of a 64x64 chunk ---
  const int srow = tid >> 2;           // 0..63
  const int sbase = (tid & 3) * 4;     // slot base 0,4,8,12
  const bool sok = srow < nrows;
  const float* xs = x + (size_t)(r0 + srow) * HID + sbase * 4;
  int lofs[4];
  #pragma unroll
  for (int j = 0; j < 4; ++j)
    lofs[j] = srow * 128 + (((sbase + j) * 8) ^ ((srow & 7) << 4));

  f32x4 pfA[4], pfB[4];

  #define ISSUE(PF, CH) do { _Pragma("unroll")                               \
    for (int j = 0; j < 4; ++j)                                              \
      PF[j] = sok ? *(const f32x4*)(xs + (CH) * BK + j * 4)                  \
                  : (f32x4){0,0,0,0}; } while(0)

  #define CVTW(PF, BUFI) do { _Pragma("unroll")                              \
    for (int j = 0; j < 4; ++j)                                              \
      *(s16x4*)((char*)Abuf + (BUFI) * (ROWS * BK * 2) + lofs[j]) =          \
          pack4(PF[j]); } while(0)

  #define BARRIER() do {                                                     \
      asm volatile("s_waitcnt lgkmcnt(0)" ::: "memory");                     \
      __builtin_amdgcn_s_barrier(); } while(0)

  if (tid < ROWS) s_lds[tid] = 0.0f;

  // --- MFMA fragment geometry: 4 waves x (64 rows x 48 cols), strip offset ---
  const int lane = tid & 63;
  const int wave = tid >> 6;          // 0..3
  const int l15 = lane & 15;
  const int lk  = lane >> 4;          // 0..3
  const int c0  = strip * 192 + wave * 48;
  const char* abase = (const char*)Abuf + l15 * 128;
  const int col0 = (lk * 16) ^ ((l15 & 7) << 4);
  const int col1 = col0 ^ 64;

  // fragment-ordered B: this block's col-tiles start at t = strip*12 + wave*3
  const short* B2 = Wb + (size_t)(strip * 12 + wave * 3) * 512 + lane * 8;

  auto loadB = [&](int n, int kc) -> s16x8 {   // kc = 32-wide chunk idx, 0..23
    return *(const s16x8*)(B2 + (size_t)kc * 24576 + n * 512);
  };

  f32x4 acc[4][3];
  #pragma unroll
  for (int m = 0; m < 4; ++m)
    #pragma unroll
    for (int n = 0; n < 3; ++n) acc[m][n] = (f32x4){0,0,0,0};

  s16x8 bE[3], bO[3];

  ISSUE(pfA, 0);
  ISSUE(pfB, 1);
  #pragma unroll
  for (int n = 0; n < 3; ++n) bE[n] = loadB(n, 0);
  CVTW(pfA, 0);
  BARRIER();

  #define CHUNK(C, PFI, ICH, PFW) do {                                       \
    const int bufi = (C) & 1;                                                \
    const char* ab = abase + bufi * (ROWS * BK * 2);                         \
    _Pragma("unroll")                                                        \
    for (int n = 0; n < 3; ++n) bO[n] = loadB(n, (C) * 2 + 1);               \
    if ((ICH) < NCH) ISSUE(PFI, ICH);                                        \
    {                                                                        \
      s16x8 a0 = *(const s16x8*)(ab + 0 * (16*128) + col0);                  \
      s16x8 a1 = *(const s16x8*)(ab + 1 * (16*128) + col0);                  \
      s16x8 a2 = *(const s16x8*)(ab + 2 * (16*128) + col0);                  \
      s16x8 a3 = *(const s16x8*)(ab + 3 * (16*128) + col0);                  \
      __builtin_amdgcn_s_setprio(1);                                         \
      _Pragma("unroll")                                                      \
      for (int n = 0; n < 3; ++n) {                                          \
        acc[0][n] = __builtin_amdgcn_mfma_f32_16x16x32_bf16(a0, bE[n], acc[0][n], 0,0,0); \
        acc[1][n] = __builtin_amdgcn_mfma_f32_16x16x32_bf16(a1, bE[n], acc[1][n], 0,0,0); \
        acc[2][n] = __builtin_amdgcn_mfma_f32_16x16x32_bf16(a2, bE[n], acc[2][n], 0,0,0); \
        acc[3][n] = __builtin_amdgcn_mfma_f32_16x16x32_bf16(a3, bE[n], acc[3][n], 0,0,0); \
      }                                                                      \
      __builtin_amdgcn_s_setprio(0);                                         \
    }                                                                        \
    {                                                                        \
      const int tn = (C) * 2 + 2;                                            \
      _Pragma("unroll")                                                      \
      for (int n = 0; n < 3; ++n) bE[n] = loadB(n, tn < 24 ? tn : 23);       \
      s16x8 a0 = *(const s16x8*)(ab + 0 * (16*128) + col1);                  \
      s16x8 a1 = *(const s16x8*)(ab + 1 * (16*128) + col1);                  \
      s16x8 a2 = *(const s16x8*)(ab + 2 * (16*128) + col1);                  \
      s16x8 a3 = *(const s16x8*)(ab + 3 * (16*128) + col1);                  \
      __builtin_amdgcn_s_setprio(1);                                         \
      _Pragma("unroll")                                                      \
      for (int n = 0; n < 3; ++n) {                                          \
        acc[0][n] = __builtin_amdgcn_mfma_f32_16x16x32_bf16(a0, bO[n], acc[0][n], 0,0,0); \
        acc[1][n] = __builtin_amdgcn_mfma_f32_16x16x32_bf16(a1, bO[n], acc[1][n], 0,0,0); \
        acc[2][n] = __builtin_amdgcn_mfma_f32_16x16x32_bf16(a2, bO[n], acc[2][n], 0,0,0); \
        acc[3][n] = __builtin_amdgcn_mfma_f32_16x16x32_bf16(a3, bO[n], acc[3][n], 0,0,0); \
      }                                                                      \
      __builtin_amdgcn_s_setprio(0);                                         \
    }                                                                        \
    if ((C) + 1 < NCH) CVTW(PFW, bufi ^ 1);                                  \
    BARRIER();                                                               \
  } while(0)

  #pragma unroll 1
  for (int ch = 0; ch < NCH; ch += 2) {
    CHUNK(ch,     pfA, ch + 2, pfB);
    CHUNK(ch + 1, pfB, ch + 3, pfA);
  }

  // --- tanh + scorer dot for this 192-col strip, reduce -> s_lds ---
  float wv[3], bv[3];
  #pragma unroll
  for (int n = 0; n < 3; ++n) {
    int col = c0 + n * 16 + l15;
    wv[n] = scw[col];
    bv[n] = bias[col];
  }
  #pragma unroll
  for (int m = 0; m < 4; ++m) {
    #pragma unroll
    for (int r = 0; r < 4; ++r) {
      float v = 0.0f;
      #pragma unroll
      for (int n = 0; n < 3; ++n)
        v += fast_tanh(acc[m][n][r] + bv[n]) * wv[n];
      v += __shfl_xor(v, 1);
      v += __shfl_xor(v, 2);
      v += __shfl_xor(v, 4);
      v += __shfl_xor(v, 8);
      if (l15 == 0) atomicAdd(&s_lds[m * 16 + lk * 4 + r], v);
    }
  }
  __syncthreads();

  // publish per-row partial logits (device-scope atomic)
  if (tid < nrows) atomicAdd(&s_glob[r0 + tid], s_lds[tid]);
  __syncthreads();

  // counter handshake: last strip-block pools this tile
  if (tid == 0) {
    __threadfence();
    int old = atomicAdd(&cnt[tile], 1);
    lastflag = (old == NSTRIP - 1) ? 1 : 0;
  }
  __syncthreads();
  if (!lastflag) return;
  __threadfence();

  if (tid < ROWS)
    s_lds[tid] = (tid < nrows)
        ? __hip_atomic_load(&s_glob[r0 + tid], __ATOMIC_RELAXED, __HIP_MEMORY_SCOPE_AGENT)
        : 0.0f;
  __syncthreads();

  // --- per-word softmax + weighted sum (x L2/L3-warm), 4 waves x 4 words ---
  const float LOG2E = 1.4426950408889634f;
  for (int wi = wave; wi < WPB; wi += 4) {
    int gw = w0 + wi;
    if (gw >= num_words) break;
    int grs = mapping[2 * gw];
    int lrs = grs - r0;
    int cnt_ = min(mapping[2 * gw + 1] - r0, nrows) - lrs;
    float mmax = -3.0e38f;
    for (int i = 0; i < cnt_; ++i) mmax = fmaxf(mmax, s_lds[lrs + i]);
    float denom = 0.0f;
    for (int i = 0; i < cnt_; ++i) denom += exp2f((s_lds[lrs + i] - mmax) * LOG2E);
    float rden = (denom > 0.0f) ? (1.0f / denom) : 0.0f;
    float pb[8];
    #pragma unroll
    for (int i = 0; i < 8; ++i)
      pb[i] = (i < cnt_) ? exp2f((s_lds[lrs + i] - mmax) * LOG2E) * rden : 0.0f;
    #pragma unroll
    for (int j = 0; j < 3; ++j) {
      int col = j * 256 + lane * 4;
      const float* xb = x + (size_t)grs * HID + col;
      f32x4 o = {0, 0, 0, 0};
      #pragma unroll
      for (int i = 0; i < 8; ++i) {
        if (i < cnt_) {
          f32x4 xv = *(const f32x4*)(xb + (size_t)i * HID);
          o[0] += pb[i] * xv[0];
          o[1] += pb[i] * xv[1];
          o[2] += pb[i] * xv[2];
          o[3] += pb[i] * xv[3];
        }
      }
      for (int i = 8; i < cnt_; ++i) {   // generality tail (unused here)
        float p = exp2f((s_lds[lrs + i] - mmax) * LOG2E) * rden;
        f32x4 xv = *(const f32x4*)(xb + (size_t)i * HID);
        o[0] += p * xv[0];
        o[1] += p * xv[1];
        o[2] += p * xv[2];
        o[3] += p * xv[3];
      }
      *(f32x4*)(out + (size_t)gw * HID + col) = o;
    }
  }
  #undef ISSUE
  #undef CVTW
  #undef BARRIER
  #undef CHUNK
}

// ==== fallback (r9 fused kernel, fp32-B path) if workspace too small ====
__global__ __launch_bounds__(1024, 1) void fused_fb(
    const float* __restrict__ x, const float* __restrict__ Wf,
    const float* __restrict__ bias, const float* __restrict__ scw,
    const int* __restrict__ mapping, float* __restrict__ out, int num_words)
{
  __shared__ short Abuf[2 * ROWS * BK];
  __shared__ float s_lds[ROWS];
  const int tid = threadIdx.x;
  const int tile = blockIdx.x;
  const int w0 = tile * WPB;
  const int wlast = min(w0 + WPB - 1, num_words - 1);
  const int r0 = mapping[2 * w0];
  const int r1 = mapping[2 * wlast + 1];
  const int nrows = min(r1 - r0, ROWS);
  const int srow = tid >> 4;
  const int sslot = tid & 15;
  const bool sok = srow < nrows;
  const float* xs = x + (size_t)(r0 + srow) * HID + sslot * 4;
  char* wsw = (char*)Abuf + srow * 128 + ((sslot * 8) ^ ((srow & 7) << 4));
  if (tid < ROWS) s_lds[tid] = 0.0f;
  const int lane = tid & 63;
  const int wave = tid >> 6;
  const int l15 = lane & 15;
  const int lk  = lane >> 4;
  const int c0  = wave * 48;
  const char* abase = (const char*)Abuf + l15 * 128;
  const int col0 = (lk * 16) ^ ((l15 & 7) << 4);
  const int col1 = col0 ^ 64;
  const float* Bf = Wf + (size_t)(c0 + l15) * HID + lk * 8;
  f32x4 acc[4][3];
  #pragma unroll
  for (int m = 0; m < 4; ++m)
    #pragma unroll
    for (int n = 0; n < 3; ++n) acc[m][n] = (f32x4){0,0,0,0};
  f32x4 pfA;
  #pragma unroll 1
  for (int ch = 0; ch < NCH; ++ch) {
    pfA = sok ? *(const f32x4*)(xs + ch * BK) : (f32x4){0,0,0,0};
    *(s16x4*)(wsw) = pack4(pfA);
    __syncthreads();
    #pragma unroll
    for (int kk = 0; kk < 2; ++kk) {
      const int kg = ch * BK + kk * 32;
      s16x8 b[3];
      #pragma unroll
      for (int n = 0; n < 3; ++n) {
        f32x4 g0 = *(const f32x4*)(Bf + n * (16 * HID) + kg);
        f32x4 g1 = *(const f32x4*)(Bf + n * (16 * HID) + kg + 4);
        b[n] = pack8(g0, g1);
      }
      #pragma unroll
      for (int m = 0; m < 4; ++m) {
        s16x8 a = *(const s16x8*)(abase + m * (16*128) + (kk ? col1 : col0));
        #pragma unroll
        for (int n = 0; n < 3; ++n)
          acc[m][n] = __builtin_amdgcn_mfma_f32_16x16x32_bf16(a, b[n], acc[m][n], 0,0,0);
      }
    }
    __syncthreads();
  }
  float wv[3], bv[3];
  #pragma unroll
  for (int n = 0; n < 3; ++n) {
    int col = c0 + n * 16 + l15;
    wv[n] = scw[col];
    bv[n] = bias[col];
  }
  #pragma unroll
  for (int m = 0; m < 4; ++m) {
    #pragma unroll
    for (int r = 0; r < 4; ++r) {
      float v = 0.0f;
      #pragma unroll
      for (int n = 0; n < 3; ++n)
        v += fast_tanh(acc[m][n][r] + bv[n]) * wv[n];
      v += __shfl_xor(v, 1);
      v += __shfl_xor(v, 2);
      v += __shfl_xor(v, 4);
      v += __shfl_xor(v, 8);
      if (l15 == 0) atomicAdd(&s_lds[m * 16 + lk * 4 + r], v);
    }
  }
  __syncthreads();
  const float LOG2E = 1.4426950408889634f;
  int gw = w0 + wave;
  if (wave < WPB && gw < num_words) {
    int grs = mapping[2 * gw];
    int lrs = grs - r0;
    int cnt_ = min(mapping[2 * gw + 1] - r0, nrows) - lrs;
    float mmax = -3.0e38f;
    for (int i = 0; i < cnt_; ++i) mmax = fmaxf(mmax, s_lds[lrs + i]);
    float denom = 0.0f;
    for (int i = 0; i < cnt_; ++i) denom += exp2f((s_lds[lrs + i] - mmax) * LOG2E);
    float rden = (denom > 0.0f) ? (1.0f / denom) : 0.0f;
    #pragma unroll
    for (int j = 0; j < 3; ++j) {
      int col = j * 256 + lane * 4;
      const float* xb = x + (size_t)grs * HID + col;
      f32x4 o = {0, 0, 0, 0};
      for (int i = 0; i < cnt_; ++i) {
        float p = exp2f((s_lds[lrs + i] - mmax) * LOG2E) * rden;
        f32x4 xv = *(const f32x4*)(xb + (size_t)i * HID);
        o[0] += p * xv[0]; o[1] += p * xv[1]; o[2] += p * xv[2]; o[3] += p * xv[3];
      }
      *(f32x4*)(out + (size_t)gw * HID + col) = o;
    }
  }
}

extern "C" void kernel_launch(void* const* d_in, const int* in_sizes, int n_in,
                              void* d_out, int out_size, void* d_ws, size_t ws_size,
                              hipStream_t stream) {
  const float* x    = (const float*)d_in[0];
  const float* W    = (const float*)d_in[1];
  const float* bias = (const float*)d_in[2];
  const float* scw  = (const float*)d_in[3];
  // d_in[4] (scorer bias) shifts every logit equally -> cancels in softmax
  const int* mapping = (const int*)d_in[5];
  float* out = (float*)d_out;

  int num_words = in_sizes[5] / 2;
  int n_sub = in_sizes[0] / HID;
  int ntiles = (num_words + WPB - 1) / WPB;

  size_t wb_bytes   = (size_t)HID * HID * sizeof(short);      // 1,179,648
  size_t sg_bytes   = (size_t)n_sub * sizeof(float);          // 1,048,576
  size_t cnt_bytes  = (size_t)ntiles * sizeof(int);           // 16,384
  size_t need = wb_bytes + sg_bytes + cnt_bytes;

  char* wsb = (char*)d_ws;
  if (ws_size >= need) {
    short* Wb     = (short*)wsb;
    float* s_glob = (float*)(wsb + wb_bytes);
    int*   cnt    = (int*)(wsb + wb_bytes + sg_bytes);
    // zero logits + counters (contiguous region)
    hipMemsetAsync(s_glob, 0, sg_bytes + cnt_bytes, stream);
    int n64 = (HID / 32) * (HID / 16) * 64;   // 73728 fragment-lane slots
    wconv_kernel<<<(n64 + 255) / 256, 256, 0, stream>>>(W, Wb, n64);
    gemm_split<<<ntiles * NSTRIP, 256, 0, stream>>>(
        x, Wb, bias, scw, mapping, out, num_words, s_glob, cnt);
  } else {
    fused_fb<<<ntiles, 1024, 0, stream>>>(x, W, bias, scw, mapping, out, num_words);
  }
}

// Round 12
// 2792.711 us; speedup vs baseline: 1.5614x; 1.5614x over previous
//
#include <hip/hip_runtime.h>

#define HID 768
#define WPB 64     // words per tile (M = 256 rows)
#define MROWS 256  // rows per tile
#define BK 64      // K-chunk width
#define NCH 12     // 768 / 64 K-chunks
#define NSTRIP 4   // 4 col-strips x 192 cols

typedef __attribute__((ext_vector_type(4))) float f32x4;
typedef __attribute__((ext_vector_type(8))) short s16x8;
typedef __attribute__((ext_vector_type(4))) short s16x4;

__device__ inline short f2bf(float f) {
  unsigned u = __builtin_bit_cast(unsigned, f);
  u = (u + 0x7fffu + ((u >> 16) & 1u)) >> 16;
  return (short)(unsigned short)u;
}
__device__ inline float fast_tanh(float v) {
  float e = exp2f(v * 2.885390081777927f);   // e^{2v}
  return 1.0f - 2.0f * __builtin_amdgcn_rcpf(e + 1.0f);
}
__device__ inline s16x8 pack8(f32x4 f0, f32x4 f1) {
  s16x8 p;
  p[0]=f2bf(f0[0]); p[1]=f2bf(f0[1]); p[2]=f2bf(f0[2]); p[3]=f2bf(f0[3]);
  p[4]=f2bf(f1[0]); p[5]=f2bf(f1[1]); p[6]=f2bf(f1[2]); p[7]=f2bf(f1[3]);
  return p;
}
__device__ inline s16x4 pack4(f32x4 f) {
  s16x4 p;
  p[0]=f2bf(f[0]); p[1]=f2bf(f[1]); p[2]=f2bf(f[2]); p[3]=f2bf(f[3]);
  return p;
}

// ---- pre-pass: W fp32 -> bf16 in MFMA FRAGMENT ORDER (verified r7-r11) ----
// frag(kc, t): k-chunk kc (32 wide), col-tile t (16 wide); 64 lanes x 16B
// contiguous. Lane l holds W[t*16 + (l&15)][kc*32 + (l>>4)*8 .. +8].
__global__ void wconv_kernel(const float* __restrict__ W, short* __restrict__ Wb, int n64) {
  int gid = blockIdx.x * blockDim.x + threadIdx.x;
  if (gid >= n64) return;                  // n64 = 24*48*64 = 73728
  int lane = gid & 63;
  int frag = gid >> 6;
  int kc = frag / 48;                      // 0..23
  int t  = frag - kc * 48;                 // 0..47
  int col = t * 16 + (lane & 15);
  int k0  = kc * 32 + (lane >> 4) * 8;
  const float* src = W + (size_t)col * HID + k0;
  f32x4 f0 = *(const f32x4*)src;
  f32x4 f1 = *(const f32x4*)(src + 4);
  *(s16x8*)(Wb + (size_t)gid * 8) = pack8(f0, f1);
}

// ==== main: M=256-row tiles x 192-col strips; B-chunk LDS-shared by 4 M-waves ====
__global__ __launch_bounds__(1024, 1) void gemm_big(
    const float* __restrict__ x, const short* __restrict__ Wb,
    const float* __restrict__ bias, const float* __restrict__ scw,
    const int* __restrict__ mapping, float* __restrict__ out,
    int num_words, float* __restrict__ s_glob, int* __restrict__ cnt)
{
  __shared__ short Abuf[2 * MROWS * BK];   // 64 KB: A bf16, r9-swizzled, dbuf
  __shared__ short Bbuf[2 * 12288];        // 48 KB: B fragments, linear, dbuf
  __shared__ float s_lds[MROWS];
  __shared__ int lastflag;

  const int tid = threadIdx.x;
  const int bid = blockIdx.x;
  const int tile = bid >> 2;
  const int strip = bid & 3;
  const int w0 = tile * WPB;
  const int wlast = min(w0 + WPB - 1, num_words - 1);
  const int r0 = mapping[2 * w0];
  const int r1 = mapping[2 * wlast + 1];
  const int nrows = min(r1 - r0, MROWS);

  // --- A staging: 4 bands; within a band the EXACT r9 zero-conflict map ---
  const int arow0 = tid >> 4;          // 0..63 (band-local row)
  const int aslot = tid & 15;          // 4-float slot
  bool rowok[4];
  #pragma unroll
  for (int it = 0; it < 4; ++it) rowok[it] = (arow0 + it * 64) < nrows;
  const float* xs0 = x + (size_t)(r0 + arow0) * HID + aslot * 4;
  const int wofs0 = arow0 * 128 + ((aslot * 8) ^ ((arow0 & 7) << 4));

  // --- B staging: 1536 16B-slots; thread -> slot tid (+ slot 1024+tid if tid<512) ---
  const int kk1 = (tid >= 768) ? 1 : 0;
  const int rr1 = tid - (kk1 ? 768 : 0);       // slot1 (kk1, rr1)
  const int rr2 = 256 + tid;                   // slot2 always kk=1 (tid<512)

  if (tid < MROWS) s_lds[tid] = 0.0f;

  // --- MFMA geometry: 16 waves = 4M x 4N; wave-tile 64 rows x 48 cols ---
  const int lane = tid & 63;
  const int wave = tid >> 6;
  const int mw = wave >> 2;            // 0..3 M-band
  const int nw = wave & 3;             // 0..3 N-subtile group
  const int l15 = lane & 15;
  const int lk  = lane >> 4;
  const char* abase = (const char*)Abuf + (mw * 64 + l15) * 128;
  const int col0 = (lk * 16) ^ ((l15 & 7) << 4);
  const int col1 = col0 ^ 64;

  f32x4 acc[4][3];
  #pragma unroll
  for (int m = 0; m < 4; ++m)
    #pragma unroll
    for (int n = 0; n < 3; ++n) acc[m][n] = (f32x4){0,0,0,0};

  // ---- prologue: stage chunk 0 into buf0 ----
  {
    s16x8 b0 = *(const s16x8*)(Wb + ((size_t)((0 + kk1) * 48 + strip * 12)) * 512 + rr1 * 8);
    s16x8 b1;
    if (wave < 8)
      b1 = *(const s16x8*)(Wb + ((size_t)(1 * 48 + strip * 12)) * 512 + rr2 * 8);
    f32x4 pa[4];
    #pragma unroll
    for (int it = 0; it < 4; ++it)
      pa[it] = rowok[it] ? *(const f32x4*)(xs0 + (size_t)it * 64 * HID) : (f32x4){0,0,0,0};
    *(s16x8*)(Bbuf + tid * 8) = b0;
    if (wave < 8) *(s16x8*)(Bbuf + (size_t)(1024 + tid) * 8) = b1;
    #pragma unroll
    for (int it = 0; it < 4; ++it)
      *(s16x4*)((char*)Abuf + wofs0 + it * 8192) = pack4(pa[it]);
    asm volatile("s_waitcnt lgkmcnt(0)" ::: "memory");
    __builtin_amdgcn_s_barrier();
  }

  // ---- K loop: depth-1 reg-staged prefetch, raw barrier (no vmcnt drain) ----
  #pragma unroll 1
  for (int ch = 0; ch < NCH; ++ch) {
    const int bufi = ch & 1;
    const bool pre = (ch + 1 < NCH);
    s16x8 pb0, pb1;
    f32x4 pa[4];
    if (pre) {
      const int c2 = 2 * (ch + 1);
      pb0 = *(const s16x8*)(Wb + ((size_t)((c2 + kk1) * 48 + strip * 12)) * 512 + rr1 * 8);
      if (wave < 8)
        pb1 = *(const s16x8*)(Wb + ((size_t)((c2 + 1) * 48 + strip * 12)) * 512 + rr2 * 8);
      #pragma unroll
      for (int it = 0; it < 4; ++it)
        pa[it] = rowok[it] ? *(const f32x4*)(xs0 + (size_t)it * 64 * HID + (ch + 1) * BK)
                           : (f32x4){0,0,0,0};
    }
    #pragma unroll
    for (int kk = 0; kk < 2; ++kk) {
      const short* bl = Bbuf + bufi * 12288 + kk * 6144 + (nw * 3) * 512 + lane * 8;
      s16x8 b0 = *(const s16x8*)(bl);
      s16x8 b1 = *(const s16x8*)(bl + 512);
      s16x8 b2 = *(const s16x8*)(bl + 1024);
      const char* ab = abase + bufi * 32768 + (kk ? col1 : col0);
      s16x8 a0 = *(const s16x8*)(ab);
      s16x8 a1 = *(const s16x8*)(ab + 2048);
      s16x8 a2 = *(const s16x8*)(ab + 4096);
      s16x8 a3 = *(const s16x8*)(ab + 6144);
      __builtin_amdgcn_s_setprio(1);
      acc[0][0] = __builtin_amdgcn_mfma_f32_16x16x32_bf16(a0, b0, acc[0][0], 0,0,0);
      acc[1][0] = __builtin_amdgcn_mfma_f32_16x16x32_bf16(a1, b0, acc[1][0], 0,0,0);
      acc[2][0] = __builtin_amdgcn_mfma_f32_16x16x32_bf16(a2, b0, acc[2][0], 0,0,0);
      acc[3][0] = __builtin_amdgcn_mfma_f32_16x16x32_bf16(a3, b0, acc[3][0], 0,0,0);
      acc[0][1] = __builtin_amdgcn_mfma_f32_16x16x32_bf16(a0, b1, acc[0][1], 0,0,0);
      acc[1][1] = __builtin_amdgcn_mfma_f32_16x16x32_bf16(a1, b1, acc[1][1], 0,0,0);
      acc[2][1] = __builtin_amdgcn_mfma_f32_16x16x32_bf16(a2, b1, acc[2][1], 0,0,0);
      acc[3][1] = __builtin_amdgcn_mfma_f32_16x16x32_bf16(a3, b1, acc[3][1], 0,0,0);
      acc[0][2] = __builtin_amdgcn_mfma_f32_16x16x32_bf16(a0, b2, acc[0][2], 0,0,0);
      acc[1][2] = __builtin_amdgcn_mfma_f32_16x16x32_bf16(a1, b2, acc[1][2], 0,0,0);
      acc[2][2] = __builtin_amdgcn_mfma_f32_16x16x32_bf16(a2, b2, acc[2][2], 0,0,0);
      acc[3][2] = __builtin_amdgcn_mfma_f32_16x16x32_bf16(a3, b2, acc[3][2], 0,0,0);
      __builtin_amdgcn_s_setprio(0);
    }
    if (pre) {
      const int bufn = bufi ^ 1;
      *(s16x8*)(Bbuf + bufn * 12288 + tid * 8) = pb0;
      if (wave < 8) *(s16x8*)(Bbuf + bufn * 12288 + (size_t)(1024 + tid) * 8) = pb1;
      #pragma unroll
      for (int it = 0; it < 4; ++it)
        *(s16x4*)((char*)Abuf + bufn * 32768 + wofs0 + it * 8192) = pack4(pa[it]);
    }
    asm volatile("s_waitcnt lgkmcnt(0)" ::: "memory");
    __builtin_amdgcn_s_barrier();
  }

  // --- tanh + scorer dot (this strip's 48 cols per wave) -> s_lds ---
  float wv[3], bv[3];
  #pragma unroll
  for (int n = 0; n < 3; ++n) {
    int col = strip * 192 + nw * 48 + n * 16 + l15;
    wv[n] = scw[col];
    bv[n] = bias[col];
  }
  #pragma unroll
  for (int m = 0; m < 4; ++m) {
    #pragma unroll
    for (int r = 0; r < 4; ++r) {
      float v = 0.0f;
      #pragma unroll
      for (int n = 0; n < 3; ++n)
        v += fast_tanh(acc[m][n][r] + bv[n]) * wv[n];
      v += __shfl_xor(v, 1);
      v += __shfl_xor(v, 2);
      v += __shfl_xor(v, 4);
      v += __shfl_xor(v, 8);
      if (l15 == 0) atomicAdd(&s_lds[mw * 64 + m * 16 + lk * 4 + r], v);
    }
  }
  __syncthreads();

  // publish this strip's partial logits (device-scope)
  if (tid < nrows) atomicAdd(&s_glob[r0 + tid], s_lds[tid]);
  __syncthreads();

  // counter handshake: last strip-block of the tile pools (r11-verified)
  if (tid == 0) {
    __threadfence();
    int old = atomicAdd(&cnt[tile], 1);
    lastflag = (old == NSTRIP - 1) ? 1 : 0;
  }
  __syncthreads();
  if (!lastflag) return;
  __threadfence();

  if (tid < MROWS)
    s_lds[tid] = (tid < nrows)
        ? __hip_atomic_load(&s_glob[r0 + tid], __ATOMIC_RELAXED, __HIP_MEMORY_SCOPE_AGENT)
        : 0.0f;
  __syncthreads();

  // --- per-word softmax + weighted sum (x L2/L3-warm), 16 waves x 4 words ---
  const float LOG2E = 1.4426950408889634f;
  for (int wi = wave; wi < WPB; wi += 16) {
    int gw = w0 + wi;
    if (gw >= num_words) break;
    int grs = mapping[2 * gw];
    int lrs = grs - r0;
    int cnt_ = min(mapping[2 * gw + 1] - r0, nrows) - lrs;
    float mmax = -3.0e38f;
    for (int i = 0; i < cnt_; ++i) mmax = fmaxf(mmax, s_lds[lrs + i]);
    float denom = 0.0f;
    for (int i = 0; i < cnt_; ++i) denom += exp2f((s_lds[lrs + i] - mmax) * LOG2E);
    float rden = (denom > 0.0f) ? (1.0f / denom) : 0.0f;
    float pb[8];
    #pragma unroll
    for (int i = 0; i < 8; ++i)
      pb[i] = (i < cnt_) ? exp2f((s_lds[lrs + i] - mmax) * LOG2E) * rden : 0.0f;
    #pragma unroll
    for (int j = 0; j < 3; ++j) {
      int col = j * 256 + lane * 4;
      const float* xb = x + (size_t)grs * HID + col;
      f32x4 o = {0, 0, 0, 0};
      #pragma unroll
      for (int i = 0; i < 8; ++i) {
        if (i < cnt_) {
          f32x4 xv = *(const f32x4*)(xb + (size_t)i * HID);
          o[0] += pb[i] * xv[0];
          o[1] += pb[i] * xv[1];
          o[2] += pb[i] * xv[2];
          o[3] += pb[i] * xv[3];
        }
      }
      for (int i = 8; i < cnt_; ++i) {   // generality tail (unused for this data)
        float p = exp2f((s_lds[lrs + i] - mmax) * LOG2E) * rden;
        f32x4 xv = *(const f32x4*)(xb + (size_t)i * HID);
        o[0] += p * xv[0];
        o[1] += p * xv[1];
        o[2] += p * xv[2];
        o[3] += p * xv[3];
      }
      *(f32x4*)(out + (size_t)gw * HID + col) = o;
    }
  }
}

// ==== fallback (fused 64-row kernel, fp32-B path) if workspace too small ====
__global__ __launch_bounds__(1024, 1) void fused_fb(
    const float* __restrict__ x, const float* __restrict__ Wf,
    const float* __restrict__ bias, const float* __restrict__ scw,
    const int* __restrict__ mapping, float* __restrict__ out, int num_words)
{
  __shared__ short Abuf[64 * BK];
  __shared__ float s_lds[64];
  const int tid = threadIdx.x;
  const int tile = blockIdx.x;
  const int w0 = tile * 16;
  const int wlast = min(w0 + 15, num_words - 1);
  const int r0 = mapping[2 * w0];
  const int r1 = mapping[2 * wlast + 1];
  const int nrows = min(r1 - r0, 64);
  const int srow = tid >> 4;
  const int sslot = tid & 15;
  const bool sok = srow < nrows;
  const float* xs = x + (size_t)(r0 + srow) * HID + sslot * 4;
  char* wsw = (char*)Abuf + srow * 128 + ((sslot * 8) ^ ((srow & 7) << 4));
  if (tid < 64) s_lds[tid] = 0.0f;
  const int lane = tid & 63;
  const int wave = tid >> 6;
  const int l15 = lane & 15;
  const int lk  = lane >> 4;
  const int c0  = wave * 48;
  const char* abase = (const char*)Abuf + l15 * 128;
  const int col0 = (lk * 16) ^ ((l15 & 7) << 4);
  const int col1 = col0 ^ 64;
  const float* Bf = Wf + (size_t)(c0 + l15) * HID + lk * 8;
  f32x4 acc[4][3];
  #pragma unroll
  for (int m = 0; m < 4; ++m)
    #pragma unroll
    for (int n = 0; n < 3; ++n) acc[m][n] = (f32x4){0,0,0,0};
  #pragma unroll 1
  for (int ch = 0; ch < NCH; ++ch) {
    f32x4 pfA = sok ? *(const f32x4*)(xs + ch * BK) : (f32x4){0,0,0,0};
    *(s16x4*)(wsw) = pack4(pfA);
    __syncthreads();
    #pragma unroll
    for (int kk = 0; kk < 2; ++kk) {
      const int kg = ch * BK + kk * 32;
      s16x8 b[3];
      #pragma unroll
      for (int n = 0; n < 3; ++n) {
        f32x4 g0 = *(const f32x4*)(Bf + n * (16 * HID) + kg);
        f32x4 g1 = *(const f32x4*)(Bf + n * (16 * HID) + kg + 4);
        b[n] = pack8(g0, g1);
      }
      #pragma unroll
      for (int m = 0; m < 4; ++m) {
        s16x8 a = *(const s16x8*)(abase + m * 2048 + (kk ? col1 : col0));
        #pragma unroll
        for (int n = 0; n < 3; ++n)
          acc[m][n] = __builtin_amdgcn_mfma_f32_16x16x32_bf16(a, b[n], acc[m][n], 0,0,0);
      }
    }
    __syncthreads();
  }
  float wv[3], bv[3];
  #pragma unroll
  for (int n = 0; n < 3; ++n) {
    int col = c0 + n * 16 + l15;
    wv[n] = scw[col];
    bv[n] = bias[col];
  }
  #pragma unroll
  for (int m = 0; m < 4; ++m) {
    #pragma unroll
    for (int r = 0; r < 4; ++r) {
      float v = 0.0f;
      #pragma unroll
      for (int n = 0; n < 3; ++n)
        v += fast_tanh(acc[m][n][r] + bv[n]) * wv[n];
      v += __shfl_xor(v, 1);
      v += __shfl_xor(v, 2);
      v += __shfl_xor(v, 4);
      v += __shfl_xor(v, 8);
      if (l15 == 0) atomicAdd(&s_lds[m * 16 + lk * 4 + r], v);
    }
  }
  __syncthreads();
  const float LOG2E = 1.4426950408889634f;
  int gw = w0 + wave;
  if (wave < 16 && gw < num_words) {
    int grs = mapping[2 * gw];
    int lrs = grs - r0;
    int cnt_ = min(mapping[2 * gw + 1] - r0, nrows) - lrs;
    float mmax = -3.0e38f;
    for (int i = 0; i < cnt_; ++i) mmax = fmaxf(mmax, s_lds[lrs + i]);
    float denom = 0.0f;
    for (int i = 0; i < cnt_; ++i) denom += exp2f((s_lds[lrs + i] - mmax) * LOG2E);
    float rden = (denom > 0.0f) ? (1.0f / denom) : 0.0f;
    #pragma unroll
    for (int j = 0; j < 3; ++j) {
      int col = j * 256 + lane * 4;
      const float* xb = x + (size_t)grs * HID + col;
      f32x4 o = {0, 0, 0, 0};
      for (int i = 0; i < cnt_; ++i) {
        float p = exp2f((s_lds[lrs + i] - mmax) * LOG2E) * rden;
        f32x4 xv = *(const f32x4*)(xb + (size_t)i * HID);
        o[0] += p * xv[0]; o[1] += p * xv[1]; o[2] += p * xv[2]; o[3] += p * xv[3];
      }
      *(f32x4*)(out + (size_t)gw * HID + col) = o;
    }
  }
}

extern "C" void kernel_launch(void* const* d_in, const int* in_sizes, int n_in,
                              void* d_out, int out_size, void* d_ws, size_t ws_size,
                              hipStream_t stream) {
  const float* x    = (const float*)d_in[0];
  const float* W    = (const float*)d_in[1];
  const float* bias = (const float*)d_in[2];
  const float* scw  = (const float*)d_in[3];
  // d_in[4] (scorer bias) shifts every logit equally -> cancels in softmax
  const int* mapping = (const int*)d_in[5];
  float* out = (float*)d_out;

  int num_words = in_sizes[5] / 2;
  int n_sub = in_sizes[0] / HID;
  int ntiles = (num_words + WPB - 1) / WPB;

  size_t wb_bytes  = (size_t)HID * HID * sizeof(short);
  size_t sg_bytes  = (size_t)n_sub * sizeof(float);
  size_t cnt_bytes = (size_t)ntiles * sizeof(int);
  size_t need = wb_bytes + sg_bytes + cnt_bytes;

  char* wsb = (char*)d_ws;
  if (ws_size >= need) {
    short* Wb     = (short*)wsb;
    float* s_glob = (float*)(wsb + wb_bytes);
    int*   cntb   = (int*)(wsb + wb_bytes + sg_bytes);
    hipMemsetAsync(s_glob, 0, sg_bytes + cnt_bytes, stream);
    int n64 = (HID / 32) * (HID / 16) * 64;
    wconv_kernel<<<(n64 + 255) / 256, 256, 0, stream>>>(W, Wb, n64);
    gemm_big<<<ntiles * NSTRIP, 1024, 0, stream>>>(
        x, Wb, bias, scw, mapping, out, num_words, s_glob, cntb);
  } else {
    int nt16 = (num_words + 15) / 16;
    fused_fb<<<nt16, 1024, 0, stream>>>(x, W, bias, scw, mapping, out, num_words);
  }
}

// Round 13
// 1300.732 us; speedup vs baseline: 3.3524x; 2.1470x over previous
//
#include <hip/hip_runtime.h>

#define HID 768
#define WPB 64     // words per tile (M = 256 rows)
#define MROWS 256
#define BK 64      // K-chunk width
#define NCH 12     // 768 / 64
#define NSTRIP 3   // 3 col-strips x 256 cols

typedef __attribute__((ext_vector_type(4))) float f32x4;
typedef __attribute__((ext_vector_type(8))) short s16x8;
typedef __attribute__((ext_vector_type(4))) short s16x4;

__device__ inline short f2bf(float f) {
  unsigned u = __builtin_bit_cast(unsigned, f);
  u = (u + 0x7fffu + ((u >> 16) & 1u)) >> 16;
  return (short)(unsigned short)u;
}
__device__ inline float fast_tanh(float v) {
  float e = exp2f(v * 2.885390081777927f);   // e^{2v}
  return 1.0f - 2.0f * __builtin_amdgcn_rcpf(e + 1.0f);
}
__device__ inline s16x8 pack8(f32x4 f0, f32x4 f1) {
  s16x8 p;
  p[0]=f2bf(f0[0]); p[1]=f2bf(f0[1]); p[2]=f2bf(f0[2]); p[3]=f2bf(f0[3]);
  p[4]=f2bf(f1[0]); p[5]=f2bf(f1[1]); p[6]=f2bf(f1[2]); p[7]=f2bf(f1[3]);
  return p;
}
__device__ inline s16x4 pack4(f32x4 f) {
  s16x4 p;
  p[0]=f2bf(f[0]); p[1]=f2bf(f[1]); p[2]=f2bf(f[2]); p[3]=f2bf(f[3]);
  return p;
}

// ---- pre-pass: W fp32 -> bf16 in MFMA FRAGMENT ORDER (verified r7-r12) ----
// frag(kc, t): k-chunk kc (32 wide), col-tile t (16 wide); 64 lanes x 16B
// contiguous. Lane l holds W[t*16 + (l&15)][kc*32 + (l>>4)*8 .. +8].
__global__ void wconv_kernel(const float* __restrict__ W, short* __restrict__ Wb, int n64) {
  int gid = blockIdx.x * blockDim.x + threadIdx.x;
  if (gid >= n64) return;                  // n64 = 24*48*64 = 73728
  int lane = gid & 63;
  int frag = gid >> 6;
  int kc = frag / 48;
  int t  = frag - kc * 48;
  int col = t * 16 + (lane & 15);
  int k0  = kc * 32 + (lane >> 4) * 8;
  const float* src = W + (size_t)col * HID + k0;
  f32x4 f0 = *(const f32x4*)src;
  f32x4 f1 = *(const f32x4*)(src + 4);
  *(s16x8*)(Wb + (size_t)gid * 8) = pack8(f0, f1);
}

// ==== main: m201 geometry. M=256 x N=256 strips, 8 waves, wave-tile 128x64 ====
__global__ __launch_bounds__(512, 2) void gemm_m201(
    const float* __restrict__ x, const short* __restrict__ Wb,
    const float* __restrict__ bias, const float* __restrict__ scw,
    const int* __restrict__ mapping, float* __restrict__ out,
    int num_words, float* __restrict__ s_glob, int* __restrict__ cnt, int swz)
{
  __shared__ short Abuf[2 * MROWS * BK];   // 64 KB: A bf16, r9-verified swizzle, dbuf
  __shared__ short Bbuf[2 * 16384];        // 64 KB: B fragments, linear, dbuf
  __shared__ float s_lds[MROWS];
  __shared__ int lastflag;

  const int tid = threadIdx.x;
  int tile, strip;
  if (swz) {                               // siblings (strips of one tile) differ by
    int q = blockIdx.x / 24;               // 8 in blockIdx -> same XCD under
    int rr = blockIdx.x - q * 24;          // round-robin dispatch -> A L2-shared
    tile = q * 8 + (rr & 7);
    strip = rr >> 3;
  } else {
    tile = blockIdx.x / NSTRIP;
    strip = blockIdx.x - tile * NSTRIP;
  }
  const int w0 = tile * WPB;
  const int wlast = min(w0 + WPB - 1, num_words - 1);
  const int r0 = mapping[2 * w0];
  const int r1 = mapping[2 * wlast + 1];
  const int nrows = min(r1 - r0, MROWS);

  // --- A staging: slot s = tid + i*512 -> row (tid>>4)+32i, 4-float slot tid&15
  //     (r9-verified 16-thread-per-row map + XOR swizzle, 0 conflicts) ---
  const int arow = tid >> 4;               // 0..31
  const int aslot = tid & 15;
  const float* xs = x + (size_t)(r0 + arow) * HID + aslot * 4;
  const int lofs = arow * 128 + ((aslot * 8) ^ ((arow & 7) << 4));
  bool rok[8];
  #pragma unroll
  for (int i = 0; i < 8; ++i) rok[i] = (arow + 32 * i) < nrows;

  if (tid < MROWS) s_lds[tid] = 0.0f;

  // --- MFMA geometry: 8 waves = 2M x 4N; wave-tile 128 rows x 64 cols ---
  const int lane = tid & 63;
  const int wave = tid >> 6;
  const int mw = wave >> 2;                // 0..1
  const int nw = wave & 3;                 // 0..3
  const int l15 = lane & 15;
  const int lk  = lane >> 4;
  const int col0 = (lk * 16) ^ ((l15 & 7) << 4);
  const int col1 = col0 ^ 64;

  f32x4 acc[8][4];
  #pragma unroll
  for (int m = 0; m < 8; ++m)
    #pragma unroll
    for (int n = 0; n < 4; ++n) acc[m][n] = (f32x4){0,0,0,0};

  f32x4 pa[8];
  s16x8 pb[4];

  #define ISSUE_A(CH) do { _Pragma("unroll")                                 \
    for (int i = 0; i < 8; ++i)                                              \
      pa[i] = rok[i] ? *(const f32x4*)(xs + (size_t)(32 * i) * HID + (CH) * BK) \
                     : (f32x4){0,0,0,0}; } while(0)

  #define ISSUE_B(CH) do { _Pragma("unroll")                                 \
    for (int i = 0; i < 4; ++i) {                                            \
      int s_ = tid + i * 512;                                                \
      int kk_ = s_ >> 10, t_ = (s_ >> 6) & 15, ln_ = s_ & 63;                \
      pb[i] = *(const s16x8*)(Wb +                                           \
          ((size_t)((CH) * 2 + kk_) * 48 + strip * 16 + t_) * 512 + ln_ * 8);\
    } } while(0)

  #define WRITE_AB(BUFI) do { _Pragma("unroll")                              \
    for (int i = 0; i < 4; ++i)                                              \
      *(s16x8*)(Bbuf + (BUFI) * 16384 + (size_t)(tid + i * 512) * 8) = pb[i];\
    _Pragma("unroll")                                                        \
    for (int i = 0; i < 8; ++i)                                              \
      *(s16x4*)((char*)Abuf + (BUFI) * 32768 + lofs + i * 4096) = pack4(pa[i]); \
    } while(0)

  #define BARRIER() do {                                                     \
      asm volatile("s_waitcnt lgkmcnt(0)" ::: "memory");                     \
      __builtin_amdgcn_s_barrier(); } while(0)

  // prologue
  ISSUE_A(0); ISSUE_B(0); WRITE_AB(0);
  BARRIER();

  #pragma unroll 1
  for (int ch = 0; ch < NCH; ++ch) {
    const int bufi = ch & 1;
    const bool pre = (ch + 1 < NCH);
    if (pre) { ISSUE_B(ch + 1); ISSUE_A(ch + 1); }
    #pragma unroll
    for (int kk = 0; kk < 2; ++kk) {
      const short* bbase = Bbuf + bufi * 16384 + kk * 8192 + nw * 2048 + lane * 8;
      s16x8 b0 = *(const s16x8*)(bbase);
      s16x8 b1 = *(const s16x8*)(bbase + 512);
      s16x8 b2 = *(const s16x8*)(bbase + 1024);
      s16x8 b3 = *(const s16x8*)(bbase + 1536);
      const char* ab = (const char*)Abuf + bufi * 32768
                     + (mw * 128 + l15) * 128 + (kk ? col1 : col0);
      __builtin_amdgcn_s_setprio(1);
      #pragma unroll
      for (int m = 0; m < 8; ++m) {
        s16x8 a = *(const s16x8*)(ab + m * 2048);
        acc[m][0] = __builtin_amdgcn_mfma_f32_16x16x32_bf16(a, b0, acc[m][0], 0,0,0);
        acc[m][1] = __builtin_amdgcn_mfma_f32_16x16x32_bf16(a, b1, acc[m][1], 0,0,0);
        acc[m][2] = __builtin_amdgcn_mfma_f32_16x16x32_bf16(a, b2, acc[m][2], 0,0,0);
        acc[m][3] = __builtin_amdgcn_mfma_f32_16x16x32_bf16(a, b3, acc[m][3], 0,0,0);
      }
      __builtin_amdgcn_s_setprio(0);
    }
    if (pre) WRITE_AB(bufi ^ 1);
    BARRIER();
  }

  // --- tanh + scorer dot (wave's 64 cols in this strip) -> s_lds ---
  float wv[4], bv[4];
  #pragma unroll
  for (int n = 0; n < 4; ++n) {
    int col = strip * 256 + nw * 64 + n * 16 + l15;
    wv[n] = scw[col];
    bv[n] = bias[col];
  }
  #pragma unroll
  for (int m = 0; m < 8; ++m) {
    #pragma unroll
    for (int r = 0; r < 4; ++r) {
      float v = 0.0f;
      #pragma unroll
      for (int n = 0; n < 4; ++n)
        v += fast_tanh(acc[m][n][r] + bv[n]) * wv[n];
      v += __shfl_xor(v, 1);
      v += __shfl_xor(v, 2);
      v += __shfl_xor(v, 4);
      v += __shfl_xor(v, 8);
      if (l15 == 0) atomicAdd(&s_lds[mw * 128 + m * 16 + lk * 4 + r], v);
    }
  }
  __syncthreads();

  // publish strip partials (device-scope), then counter handshake (r11-verified)
  if (tid < nrows) atomicAdd(&s_glob[r0 + tid], s_lds[tid]);
  __syncthreads();
  if (tid == 0) {
    __threadfence();
    int old = atomicAdd(&cnt[tile], 1);
    lastflag = (old == NSTRIP - 1) ? 1 : 0;
  }
  __syncthreads();
  if (!lastflag) return;
  __threadfence();

  if (tid < MROWS)
    s_lds[tid] = (tid < nrows)
        ? __hip_atomic_load(&s_glob[r0 + tid], __ATOMIC_RELAXED, __HIP_MEMORY_SCOPE_AGENT)
        : 0.0f;
  __syncthreads();

  // --- per-word softmax + weighted sum (x L2/L3-warm), 8 waves x 8 words ---
  const float LOG2E = 1.4426950408889634f;
  for (int wi = wave; wi < WPB; wi += 8) {
    int gw = w0 + wi;
    if (gw >= num_words) break;
    int grs = mapping[2 * gw];
    int lrs = grs - r0;
    int cnt_ = min(mapping[2 * gw + 1] - r0, nrows) - lrs;
    float mmax = -3.0e38f;
    for (int i = 0; i < cnt_; ++i) mmax = fmaxf(mmax, s_lds[lrs + i]);
    float denom = 0.0f;
    for (int i = 0; i < cnt_; ++i) denom += exp2f((s_lds[lrs + i] - mmax) * LOG2E);
    float rden = (denom > 0.0f) ? (1.0f / denom) : 0.0f;
    float pbuf[8];
    #pragma unroll
    for (int i = 0; i < 8; ++i)
      pbuf[i] = (i < cnt_) ? exp2f((s_lds[lrs + i] - mmax) * LOG2E) * rden : 0.0f;
    #pragma unroll
    for (int j = 0; j < 3; ++j) {
      int col = j * 256 + lane * 4;
      const float* xb = x + (size_t)grs * HID + col;
      f32x4 o = {0, 0, 0, 0};
      #pragma unroll
      for (int i = 0; i < 8; ++i) {
        if (i < cnt_) {
          f32x4 xv = *(const f32x4*)(xb + (size_t)i * HID);
          o[0] += pbuf[i] * xv[0];
          o[1] += pbuf[i] * xv[1];
          o[2] += pbuf[i] * xv[2];
          o[3] += pbuf[i] * xv[3];
        }
      }
      for (int i = 8; i < cnt_; ++i) {   // generality tail (unused for this data)
        float p = exp2f((s_lds[lrs + i] - mmax) * LOG2E) * rden;
        f32x4 xv = *(const f32x4*)(xb + (size_t)i * HID);
        o[0] += p * xv[0];
        o[1] += p * xv[1];
        o[2] += p * xv[2];
        o[3] += p * xv[3];
      }
      *(f32x4*)(out + (size_t)gw * HID + col) = o;
    }
  }
  #undef ISSUE_A
  #undef ISSUE_B
  #undef WRITE_AB
  #undef BARRIER
}

// ==== fallback (fused 64-row kernel, fp32-B path) if workspace too small ====
__global__ __launch_bounds__(1024, 1) void fused_fb(
    const float* __restrict__ x, const float* __restrict__ Wf,
    const float* __restrict__ bias, const float* __restrict__ scw,
    const int* __restrict__ mapping, float* __restrict__ out, int num_words)
{
  __shared__ short Abuf[64 * BK];
  __shared__ float s_lds[64];
  const int tid = threadIdx.x;
  const int tile = blockIdx.x;
  const int w0 = tile * 16;
  const int wlast = min(w0 + 15, num_words - 1);
  const int r0 = mapping[2 * w0];
  const int r1 = mapping[2 * wlast + 1];
  const int nrows = min(r1 - r0, 64);
  const int srow = tid >> 4;
  const int sslot = tid & 15;
  const bool sok = srow < nrows;
  const float* xs = x + (size_t)(r0 + srow) * HID + sslot * 4;
  char* wsw = (char*)Abuf + srow * 128 + ((sslot * 8) ^ ((srow & 7) << 4));
  if (tid < 64) s_lds[tid] = 0.0f;
  const int lane = tid & 63;
  const int wave = tid >> 6;
  const int l15 = lane & 15;
  const int lk  = lane >> 4;
  const int c0  = wave * 48;
  const char* abase = (const char*)Abuf + l15 * 128;
  const int col0 = (lk * 16) ^ ((l15 & 7) << 4);
  const int col1 = col0 ^ 64;
  const float* Bf = Wf + (size_t)(c0 + l15) * HID + lk * 8;
  f32x4 acc[4][3];
  #pragma unroll
  for (int m = 0; m < 4; ++m)
    #pragma unroll
    for (int n = 0; n < 3; ++n) acc[m][n] = (f32x4){0,0,0,0};
  #pragma unroll 1
  for (int ch = 0; ch < NCH; ++ch) {
    f32x4 pfA = sok ? *(const f32x4*)(xs + ch * BK) : (f32x4){0,0,0,0};
    *(s16x4*)(wsw) = pack4(pfA);
    __syncthreads();
    #pragma unroll
    for (int kk = 0; kk < 2; ++kk) {
      const int kg = ch * BK + kk * 32;
      s16x8 b[3];
      #pragma unroll
      for (int n = 0; n < 3; ++n) {
        f32x4 g0 = *(const f32x4*)(Bf + n * (16 * HID) + kg);
        f32x4 g1 = *(const f32x4*)(Bf + n * (16 * HID) + kg + 4);
        b[n] = pack8(g0, g1);
      }
      #pragma unroll
      for (int m = 0; m < 4; ++m) {
        s16x8 a = *(const s16x8*)(abase + m * 2048 + (kk ? col1 : col0));
        #pragma unroll
        for (int n = 0; n < 3; ++n)
          acc[m][n] = __builtin_amdgcn_mfma_f32_16x16x32_bf16(a, b[n], acc[m][n], 0,0,0);
      }
    }
    __syncthreads();
  }
  float wv[3], bv[3];
  #pragma unroll
  for (int n = 0; n < 3; ++n) {
    int col = c0 + n * 16 + l15;
    wv[n] = scw[col];
    bv[n] = bias[col];
  }
  #pragma unroll
  for (int m = 0; m < 4; ++m) {
    #pragma unroll
    for (int r = 0; r < 4; ++r) {
      float v = 0.0f;
      #pragma unroll
      for (int n = 0; n < 3; ++n)
        v += fast_tanh(acc[m][n][r] + bv[n]) * wv[n];
      v += __shfl_xor(v, 1);
      v += __shfl_xor(v, 2);
      v += __shfl_xor(v, 4);
      v += __shfl_xor(v, 8);
      if (l15 == 0) atomicAdd(&s_lds[m * 16 + lk * 4 + r], v);
    }
  }
  __syncthreads();
  const float LOG2E = 1.4426950408889634f;
  int gw = w0 + wave;
  if (wave < 16 && gw < num_words) {
    int grs = mapping[2 * gw];
    int lrs = grs - r0;
    int cnt_ = min(mapping[2 * gw + 1] - r0, nrows) - lrs;
    float mmax = -3.0e38f;
    for (int i = 0; i < cnt_; ++i) mmax = fmaxf(mmax, s_lds[lrs + i]);
    float denom = 0.0f;
    for (int i = 0; i < cnt_; ++i) denom += exp2f((s_lds[lrs + i] - mmax) * LOG2E);
    float rden = (denom > 0.0f) ? (1.0f / denom) : 0.0f;
    #pragma unroll
    for (int j = 0; j < 3; ++j) {
      int col = j * 256 + lane * 4;
      const float* xb = x + (size_t)grs * HID + col;
      f32x4 o = {0, 0, 0, 0};
      for (int i = 0; i < cnt_; ++i) {
        float p = exp2f((s_lds[lrs + i] - mmax) * LOG2E) * rden;
        f32x4 xv = *(const f32x4*)(xb + (size_t)i * HID);
        o[0] += p * xv[0]; o[1] += p * xv[1]; o[2] += p * xv[2]; o[3] += p * xv[3];
      }
      *(f32x4*)(out + (size_t)gw * HID + col) = o;
    }
  }
}

extern "C" void kernel_launch(void* const* d_in, const int* in_sizes, int n_in,
                              void* d_out, int out_size, void* d_ws, size_t ws_size,
                              hipStream_t stream) {
  const float* x    = (const float*)d_in[0];
  const float* W    = (const float*)d_in[1];
  const float* bias = (const float*)d_in[2];
  const float* scw  = (const float*)d_in[3];
  // d_in[4] (scorer bias) shifts every logit equally -> cancels in softmax
  const int* mapping = (const int*)d_in[5];
  float* out = (float*)d_out;

  int num_words = in_sizes[5] / 2;
  int n_sub = in_sizes[0] / HID;
  int ntiles = (num_words + WPB - 1) / WPB;

  size_t wb_bytes  = (size_t)HID * HID * sizeof(short);
  size_t sg_bytes  = (size_t)n_sub * sizeof(float);
  size_t cnt_bytes = (size_t)ntiles * sizeof(int);
  size_t need = wb_bytes + sg_bytes + cnt_bytes;

  char* wsb = (char*)d_ws;
  if (ws_size >= need) {
    short* Wb     = (short*)wsb;
    float* s_glob = (float*)(wsb + wb_bytes);
    int*   cntb   = (int*)(wsb + wb_bytes + sg_bytes);
    hipMemsetAsync(s_glob, 0, sg_bytes + cnt_bytes, stream);
    int n64 = (HID / 32) * (HID / 16) * 64;
    wconv_kernel<<<(n64 + 255) / 256, 256, 0, stream>>>(W, Wb, n64);
    int swz = (ntiles % 8 == 0) ? 1 : 0;
    gemm_m201<<<ntiles * NSTRIP, 512, 0, stream>>>(
        x, Wb, bias, scw, mapping, out, num_words, s_glob, cntb, swz);
  } else {
    int nt16 = (num_words + 15) / 16;
    fused_fb<<<nt16, 1024, 0, stream>>>(x, W, bias, scw, mapping, out, num_words);
  }
}